// Round 17
// baseline (367.277 us; speedup 1.0000x reference)
//
#include <hip/hip_runtime.h>
#include <stdint.h>

#define NBLOCKS 1024
#define WPB 4                          // 256 threads, 4 independent waves
#define SLOTS (NBLOCKS * WPB)          // 4096 wave slots
#define TR 16                          // rows per wave-tile (N % 16 == 0)
#define LDSW 8192                      // per-wave pool cache: 16 rows x 512 B
#define SMEM_BYTES (WPB * LDSW)        // 32 KB -> 4 blocks/CU (VGPR-capped)

typedef __attribute__((ext_vector_type(8))) short bfrag_t;
typedef __attribute__((ext_vector_type(4))) float f32x4;
typedef __attribute__((ext_vector_type(2))) unsigned int u32x2;

static __device__ __forceinline__ unsigned short f2bf(float f) {
  unsigned int u = __float_as_uint(f);
  u += 0x7fffu + ((u >> 16) & 1u);   // RNE
  return (unsigned short)(u >> 16);
}

static __device__ __forceinline__ float tanh_fast(float s) {
  // tanh(s) = 1 - 2/(1+e^{2s}); saturates at +-1, no clamp needed
  float e = __builtin_exp2f(s * 2.8853900817779268f);
  float r = __builtin_amdgcn_rcpf(1.f + e);
  return __builtin_fmaf(-2.f, r, 1.f);
}

// readlane for floats: BIT-cast (int builtin; float would value-truncate — r4 bug)
static __device__ __forceinline__ float readlane_f(float v, int l) {
  return __uint_as_float(__builtin_amdgcn_readlane(__float_as_uint(v), l));
}

static __device__ __forceinline__ bfrag_t pack8(f32x4 a, f32x4 b) {
  union { bfrag_t v; unsigned int u[4]; } r;
  asm("v_cvt_pk_bf16_f32 %0, %1, %2" : "=v"(r.u[0]) : "v"(a[0]), "v"(a[1]));
  asm("v_cvt_pk_bf16_f32 %0, %1, %2" : "=v"(r.u[1]) : "v"(a[2]), "v"(a[3]));
  asm("v_cvt_pk_bf16_f32 %0, %1, %2" : "=v"(r.u[2]) : "v"(b[0]), "v"(b[1]));
  asm("v_cvt_pk_bf16_f32 %0, %1, %2" : "=v"(r.u[3]) : "v"(b[2]), "v"(b[3]));
  return r.v;
}

#define KEEPA(A) asm volatile("" : "+v"(A[0]), "+v"(A[1]), "+v"(A[2]), "+v"(A[3]), \
                                    "+v"(A[4]), "+v"(A[5]), "+v"(A[6]), "+v"(A[7]))

// Pre-swizzle W1 (f32 [256][256], k-major) into MFMA B-fragment order, bf16.
// W1f[((cc*8+kk)*64 + lane)*8 + j] = bf16(W1[kk*32 + 8*(lane>>4) + j][cc*16 + (lane&15)])
__global__ void prep_w1_kernel(const float* __restrict__ W1, unsigned short* __restrict__ W1f) {
  const int bx = blockIdx.x;   // cc*8 + kk, 0..127
  const int l = threadIdx.x;   // 0..63
  const int cc = bx >> 3, kk = bx & 7;
  const int h = cc * 16 + (l & 15);
  const int kbase = kk * 32 + ((l >> 4) << 3);
  bfrag_t pk;
#pragma unroll
  for (int j = 0; j < 8; ++j) pk[j] = (short)f2bf(W1[(size_t)(kbase + j) * 256 + h]);
  *(bfrag_t*)(W1f + (size_t)(bx * 64 + l) * 8) = pk;
}

__launch_bounds__(256, 4)
__global__ void attnpool_kernel(const float* __restrict__ x,
                                const int* __restrict__ batch,
                                const unsigned short* __restrict__ W1f,
                                const float* __restrict__ b1,
                                const float* __restrict__ W2,
                                const float* __restrict__ b2,
                                float* __restrict__ out,   // raw weighted sums (zeroed)
                                float* __restrict__ Zp,    // softmax denominator (zeroed)
                                int N, int base, int rem) {
  extern __shared__ char smem[];
  const int t = threadIdx.x;
  const int lane = t & 63;
  const int wv = t >> 6;
  const int l15 = lane & 15;
  const int hi = lane >> 4;

  char* xb = smem + wv * LDSW;   // this wave's PRIVATE 16x256 bf16 pool cache

  const int slot = blockIdx.x * WPB + wv;
  const int cnt = base + (slot < rem ? 1 : 0);
  const int tile0 = slot * base + min(slot, rem);

  // per-lane constants (L2-hot, read once)
  float b1v[16], w2v[16];
#pragma unroll
  for (int cc = 0; cc < 16; ++cc) {
    b1v[cc] = b1[cc * 16 + l15];
    w2v[cc] = W2[cc * 16 + l15];
  }
  const float b2c = b2[0];
  const bfrag_t* Wf = (const bfrag_t*)W1f;

  float zacc = 0.f;
  f32x4 pacc = {0.f, 0.f, 0.f, 0.f};
  int gcur = -1;

  auto flush = [&]() {
    float* po = out + (size_t)gcur * 256 + lane * 4;
    atomicAdd(po + 0, pacc[0]); atomicAdd(po + 1, pacc[1]);
    atomicAdd(po + 2, pacc[2]); atomicAdd(po + 3, pacc[3]);
    pacc[0] = pacc[1] = pacc[2] = pacc[3] = 0.f;
  };

  for (int tt = 0; tt < cnt; ++tt) {
    const int tile = tile0 + tt;
    const int R0 = tile * TR;

    int bid = batch[R0 + l15];   // N % 16 == 0: in range

    // ---- A-frags: row l15, f32 global -> bf16 regs ----
    bfrag_t A0[8];
    {
      const float* p0 = x + (size_t)(R0 + l15) * 256 + hi * 8;
#pragma unroll
      for (int kk = 0; kk < 8; ++kk) {
        const f32x4 u0 = *(const f32x4*)(p0 + kk * 32);
        const f32x4 u1 = *(const f32x4*)(p0 + kk * 32 + 4);
        A0[kk] = pack8(u0, u1);
      }
    }

    // ---- write pool cache (swizzled; aggregate conflict-free) ----
    {
      const int sw = (l15 & 7) << 4;
#pragma unroll
      for (int kk = 0; kk < 8; ++kk)
        *(bfrag_t*)(xb + l15 * 512 + ((kk * 64 + hi * 16) ^ sw)) = A0[kk];
    }

    // ---- score: cc-outer MFMA, B streamed from L2-resident W1f ----
    float s0v[4] = {0.f, 0.f, 0.f, 0.f};
#pragma unroll 2
    for (int cc = 0; cc < 16; ++cc) {
      KEEPA(A0);   // pin A in regs: remat/sink impossible (r5-proven)
      f32x4 acc = {0.f, 0.f, 0.f, 0.f};
#pragma unroll
      for (int kk = 0; kk < 8; ++kk) {
        const bfrag_t Bk = Wf[(cc * 8 + kk) * 64 + lane];
        acc = __builtin_amdgcn_mfma_f32_16x16x32_bf16(A0[kk], Bk, acc, 0, 0, 0);
      }
#pragma unroll
      for (int r = 0; r < 4; ++r)
        s0v[r] += tanh_fast(acc[r] + b1v[cc]) * w2v[cc];
    }

    // ---- softmax weights: reduce over l15; w = exp(score + b2) ----
    f32x4 w0v;
#pragma unroll
    for (int r = 0; r < 4; ++r) {
      float v = s0v[r];
      v += __shfl_xor(v, 1); v += __shfl_xor(v, 2);
      v += __shfl_xor(v, 4); v += __shfl_xor(v, 8);
      w0v[r] = __expf(v + b2c);   // N % 16 == 0: all rows valid
    }
    {
      float z = (l15 == 0) ? (w0v[0] + w0v[1] + w0v[2] + w0v[3]) : 0.f;
      z += __shfl_xor(z, 16);
      z += __shfl_xor(z, 32);
      zacc += z;
    }

    // wlane: lane L holds w[row (L&15)]; row = hi*4 + r in C/D layout
    float wlane;
    {
      const int rq = lane & 3;
      const float ca = (rq == 0) ? w0v[0] : w0v[1];
      const float cb = (rq == 2) ? w0v[2] : w0v[3];
      const float c = (rq < 2) ? ca : cb;
      const int srcl = (((lane >> 2) & 3) << 4) + rq;
      wlane = __shfl(c, srcl);
    }

    // ---- pool 16 rows from private LDS; lane owns bf16 cols 4*lane..+3 ----
    const int g_first = __builtin_amdgcn_readlane(bid, 0);
    const int g_last = __builtin_amdgcn_readlane(bid, 15);
    if (g_first != gcur) { if (gcur >= 0) flush(); gcur = g_first; }
    if (g_first == g_last) {
#pragma unroll
      for (int r = 0; r < TR; ++r) {
        const float wr = readlane_f(wlane, r);
        const u32x2 v = *(const u32x2*)(xb + r * 512 + ((lane * 8) ^ ((r & 7) << 4)));
        pacc[0] = __builtin_fmaf(wr, __uint_as_float(v[0] << 16), pacc[0]);
        pacc[1] = __builtin_fmaf(wr, __uint_as_float(v[0] & 0xffff0000u), pacc[1]);
        pacc[2] = __builtin_fmaf(wr, __uint_as_float(v[1] << 16), pacc[2]);
        pacc[3] = __builtin_fmaf(wr, __uint_as_float(v[1] & 0xffff0000u), pacc[3]);
      }
    } else {
      for (int r = 0; r < TR; ++r) {
        const int g = __builtin_amdgcn_readlane(bid, r);
        if (g != gcur) { flush(); gcur = g; }
        const float wr = readlane_f(wlane, r);
        const u32x2 v = *(const u32x2*)(xb + r * 512 + ((lane * 8) ^ ((r & 7) << 4)));
        pacc[0] = __builtin_fmaf(wr, __uint_as_float(v[0] << 16), pacc[0]);
        pacc[1] = __builtin_fmaf(wr, __uint_as_float(v[0] & 0xffff0000u), pacc[1]);
        pacc[2] = __builtin_fmaf(wr, __uint_as_float(v[1] << 16), pacc[2]);
        pacc[3] = __builtin_fmaf(wr, __uint_as_float(v[1] & 0xffff0000u), pacc[3]);
      }
    }
  }

  if (gcur >= 0) flush();
  if (lane == 0 && zacc != 0.f) atomicAdd(Zp, zacc);
}

__global__ void finalize_kernel(float* __restrict__ out, const float* __restrict__ Zp, int n4) {
  const int i = blockIdx.x * blockDim.x + threadIdx.x;
  if (i < n4) {
    const float zi = 1.f / Zp[0];
    f32x4* p = (f32x4*)out;
    f32x4 v = p[i];
    v[0] *= zi; v[1] *= zi; v[2] *= zi; v[3] *= zi;
    p[i] = v;
  }
}

extern "C" void kernel_launch(void* const* d_in, const int* in_sizes, int n_in,
                              void* d_out, int out_size, void* d_ws, size_t ws_size,
                              hipStream_t stream) {
  const float* x  = (const float*)d_in[0];
  const int* batch = (const int*)d_in[1];
  const float* W1 = (const float*)d_in[2];
  const float* b1 = (const float*)d_in[3];
  const float* W2 = (const float*)d_in[4];
  const float* b2 = (const float*)d_in[5];
  float* out = (float*)d_out;
  const int N = in_sizes[1];

  unsigned short* W1f = (unsigned short*)d_ws;          // 128 KB
  float* Zp = (float*)((char*)d_ws + 131072);           // 4 B

  static int attr_done = 0;  // host-side only; idempotent attribute, not kernel state
  if (!attr_done) {
    hipFuncSetAttribute((const void*)attnpool_kernel,
                        hipFuncAttributeMaxDynamicSharedMemorySize, SMEM_BYTES);
    attr_done = 1;
  }

  const int ntiles = (N + TR - 1) / TR;
  const int base = ntiles / SLOTS;
  const int rem = ntiles % SLOTS;

  hipMemsetAsync(d_out, 0, (size_t)out_size * sizeof(float), stream);
  hipMemsetAsync(Zp, 0, sizeof(float), stream);
  prep_w1_kernel<<<128, 64, 0, stream>>>(W1, W1f);
  attnpool_kernel<<<NBLOCKS, 256, SMEM_BYTES, stream>>>(x, batch, W1f, b1, W2, b2,
                                                        out, Zp, N, base, rem);
  finalize_kernel<<<(out_size / 4 + 255) / 256, 256, 0, stream>>>(out, Zp, out_size / 4);
}